// Round 12
// baseline (56.148 us; speedup 1.0000x reference)
//
#include <hip/hip_runtime.h>

// ConvCapsuleLayer r12: r11 + forced conv load batching via sched_barrier(0).
// Per kh: issue 5 afrag (LDS) + 10 bfrag (L2) loads, hard scheduling fence,
// then 10 MFMAs -> >=15 loads in flight, L2 latency paid once per kh.
// Routing (scale-factored squash, fdot2, shfl-free agreement) unchanged from r11.

typedef __attribute__((ext_vector_type(2))) _Float16 f16x2;
typedef __attribute__((ext_vector_type(8))) _Float16 f16x8;
typedef __attribute__((ext_vector_type(16))) float f32x16;

union f16x8u { f16x8 v; f16x2 d[4]; unsigned short s[8]; unsigned int u32[4]; unsigned long long u[2]; };
union f16x2u { f16x2 v; unsigned int u; unsigned short s[2]; };

__device__ __forceinline__ unsigned short f2h(float x) {
  union { _Float16 h; unsigned short u; } v;
  v.h = (_Float16)x;
  return v.u;
}

// W[5][5][16][256] f32 -> wsh fp16 [khkw 25][ch 256][ia 16]
__global__ __launch_bounds__(256) void wprep_kernel(
    const float* __restrict__ W, unsigned short* __restrict__ wsh) {
  int t = blockIdx.x * 256 + threadIdx.x;      // 102400 total
  int khkw = t >> 12;
  int rem  = t & 4095;
  int ch = rem >> 4, ia = rem & 15;
  wsh[t] = f2h(W[khkw * 4096 + ia * 256 + ch]);
}

// LDS map (21120 B):
//   conv phase:  X fp16 [kh 5][ii 8, stride 272B][wl 8][ia 16] = 10880 B @0
//   routing:     votesT fp16 [w 4, stride 4352][ii 8, stride 544][chunk 32][a 8] @0
//                  chunk(q,c,ii) = q*8 + (((c+q)&7) ^ ii); stride 544 => banked <=2-way
//                preT  fp16 [w 4][q 4][c 8][a 8] = 2048 @17408
//                logitL f32 [w 4][ii 8][c 8]     = 1024 @19456
//                routeH fp16 [w 4][c 8][ii 8]    =  512 @20480
//                scaleL f32 [w 4][c 8]           =  128 @20992
__global__ __launch_bounds__(256, 2) void capsconv_mfma_kernel(
    const float* __restrict__ inp,            // [16][32][32][8][16] f32
    const unsigned short* __restrict__ wsh,   // [25][256][16] fp16
    const float* __restrict__ bias,           // [256] f32
    float* __restrict__ out)                  // [16][32][32][256] f32
{
  __shared__ char smem[21120];
  const _Float16* wshh = (const _Float16*)wsh;
  float* logitL = (float*)(smem + 19456);
  float* scaleL = (float*)(smem + 20992);

  const int tid  = threadIdx.x;
  const int wid  = tid >> 6;          // wave 0..3 -> ch quarter
  const int lane = tid & 63;
  const int sub  = lane >> 5;
  const int ln31 = lane & 31;

  const int bid = blockIdx.x;         // 4096 = ((bb*32 + h)*8 + wq)
  const int wq = bid & 7;
  const int h  = (bid >> 3) & 31;
  const int bb = bid >> 8;
  const int i_src  = bb >> 1;         // TF reshape scramble (verified r1/r4)
  const int b_base = (bb & 1) * 8;

  // ---------------- stage 5 X rows, PO2 decode (1280 quads) ----------------
  #pragma unroll
  for (int s = 0; s < 5; ++s) {
    int e = tid + s * 256;
    int kh  = e >> 8;
    int ii  = (e >> 5) & 7;
    int wl  = (e >> 2) & 7;
    int iaq = e & 3;
    int hh = h + kh - 2;
    int wsrc = wq * 4 + wl - 2;
    float4 v = make_float4(0.f, 0.f, 0.f, 0.f);
    if ((unsigned)hh < 32u && (unsigned)wsrc < 32u)
      v = *(const float4*)(inp +
          ((((size_t)(b_base + ii) * 32 + hh) * 32 + wsrc) * 8 + i_src) * 16 + iaq * 4);
    union { _Float16 hx[4]; unsigned long long u; } pkk;
    pkk.hx[0] = (_Float16)v.x; pkk.hx[1] = (_Float16)v.y;
    pkk.hx[2] = (_Float16)v.z; pkk.hx[3] = (_Float16)v.w;
    *(unsigned long long*)(smem + kh * 2176 + ii * 272 + wl * 32 + iaq * 8) = pkk.u;
  }
  __syncthreads();

  // ---------------- conv: 25 taps; per-kh batched loads + sched fence ----------------
  f32x16 acc[2];
  #pragma unroll
  for (int nt = 0; nt < 2; ++nt)
    #pragma unroll
    for (int e = 0; e < 16; ++e) acc[nt][e] = 0.f;

  const char* aBase = smem + (ln31 & 7) * 272 + (ln31 >> 3) * 32 + sub * 16;
  const _Float16* bBase = wshh + (wid * 64 + ln31) * 16 + sub * 8;

  #pragma unroll
  for (int kh = 0; kh < 5; ++kh) {
    f16x8 af[5], bf0[5], bf1[5];
    #pragma unroll
    for (int kw = 0; kw < 5; ++kw) {
      af[kw]  = *(const f16x8*)(aBase + kh * 2176 + kw * 32);
      bf0[kw] = *(const f16x8*)(bBase + (size_t)(kh * 5 + kw) * 4096);
      bf1[kw] = *(const f16x8*)(bBase + (size_t)(kh * 5 + kw) * 4096 + 512);
    }
    __builtin_amdgcn_sched_barrier(0);   // loads stay above; MFMAs below
    #pragma unroll
    for (int kw = 0; kw < 5; ++kw) {
      acc[0] = __builtin_amdgcn_mfma_f32_32x32x16_f16(af[kw], bf0[kw], acc[0], 0, 0, 0);
      acc[1] = __builtin_amdgcn_mfma_f32_32x32x16_f16(af[kw], bf1[kw], acc[1], 0, 0, 0);
    }
  }

  // ---------------- pack acc -> fp16 pairs; assemble vreg via lane^32 shfl ----------------
  unsigned int pk[2][4][2];
  #pragma unroll
  for (int nt = 0; nt < 2; ++nt)
    #pragma unroll
    for (int w = 0; w < 4; ++w) {
      f16x2u lo, hi;
      lo.v = f16x2{(_Float16)acc[nt][w * 4 + 0], (_Float16)acc[nt][w * 4 + 1]};
      hi.v = f16x2{(_Float16)acc[nt][w * 4 + 2], (_Float16)acc[nt][w * 4 + 3]};
      pk[nt][w][0] = lo.u; pk[nt][w][1] = hi.u;
    }
  f16x8 vreg[4];   // vreg[w].s[ii] = vote(w, ii, ch = tid)
  #pragma unroll
  for (int w = 0; w < 4; ++w) {
    unsigned int own0 = sub ? pk[1][w][0] : pk[0][w][0];
    unsigned int own1 = sub ? pk[1][w][1] : pk[0][w][1];
    unsigned int snd0 = sub ? pk[0][w][0] : pk[1][w][0];
    unsigned int snd1 = sub ? pk[0][w][1] : pk[1][w][1];
    unsigned int rc0 = (unsigned int)__shfl_xor((int)snd0, 32, 64);
    unsigned int rc1 = (unsigned int)__shfl_xor((int)snd1, 32, 64);
    f16x8u vv;
    vv.u32[0] = sub ? rc0 : own0;   // ii 0,1
    vv.u32[1] = sub ? rc1 : own1;   // ii 2,3
    vv.u32[2] = sub ? own0 : rc0;   // ii 4,5
    vv.u32[3] = sub ? own1 : rc1;   // ii 6,7
    vreg[w] = vv.v;
  }

  // ---------------- votesT writes (transpose for agreement) ----------------
  __syncthreads();   // X region dead; votesT aliases it
  {
    const int cT = (tid >> 5) & 7, qT = (tid >> 3) & 3, aT = tid & 7;
    #pragma unroll
    for (int w = 0; w < 4; ++w) {
      f16x8u vv; vv.v = vreg[w];
      #pragma unroll
      for (int ii = 0; ii < 8; ++ii) {
        int bp = qT * 8 + (((cT + qT) & 7) ^ ii);
        *(unsigned short*)(smem + w * 4352 + ii * 544 + bp * 16 + aT * 2) = vv.s[ii];
      }
    }
  }
  ((unsigned short*)(smem + 20480))[tid] = 0x3000;   // routeH = 0.125 (exact fp16)
  __syncthreads();

  // ---------------- routing ----------------
  const int c_t = (tid >> 5) & 7;
  const int q_t = (tid >> 3) & 3;
  const int a_t = tid & 7;
  const float bv = bias[tid];
  const int aw  = tid >> 6;           // agreement task (w, ii, c)
  const int aii = (tid >> 3) & 7;
  const int ac  = tid & 7;

  float pre[4];
  #pragma unroll 1
  for (int rt = 0; rt < 3; ++rt) {
    if (rt > 0) {
      if (tid < 32) {                 // softmax over c per (w, ii)
        int wv = tid >> 3, ii = tid & 7;
        float l[8];
        #pragma unroll
        for (int c = 0; c < 8; ++c) l[c] = logitL[(wv * 8 + ii) * 8 + c];
        float mx = fmaxf(fmaxf(fmaxf(l[0], l[1]), fmaxf(l[2], l[3])),
                         fmaxf(fmaxf(l[4], l[5]), fmaxf(l[6], l[7])));
        float den = 0.f;
        #pragma unroll
        for (int c = 0; c < 8; ++c) den += __expf(l[c] - mx);
        float inv = 1.f / den;
        #pragma unroll
        for (int c = 0; c < 8; ++c)
          ((unsigned short*)(smem + 20480))[(wv * 8 + c) * 8 + ii] =
              f2h(__expf(l[c] - mx) * inv);
      }
      __syncthreads();
    }
    // weighted sum; write pre (NOT act) to preT
    #pragma unroll
    for (int w = 0; w < 4; ++w) {
      f16x8u rp, vv;
      rp.v = *(const f16x8*)(smem + 20480 + ((w * 8 + c_t) * 8) * 2);
      vv.v = vreg[w];
      float p = bv;
      #pragma unroll
      for (int d = 0; d < 4; ++d)
        p = __builtin_amdgcn_fdot2(vv.d[d], rp.d[d], p, false);
      pre[w] = p;
      *(unsigned short*)(smem + 17408 + w * 512 + q_t * 128 + c_t * 16 + a_t * 2) = f2h(p);
    }
    __syncthreads();
    // squash scale per (w,c): 32 threads, 16 independent fdot2
    if (tid < 32) {
      int wv = tid >> 3, cc = tid & 7;
      const char* pp = smem + 17408 + wv * 512 + cc * 16;
      f16x8u x0, x1, x2, x3;
      x0.v = *(const f16x8*)(pp);
      x1.v = *(const f16x8*)(pp + 128);
      x2.v = *(const f16x8*)(pp + 256);
      x3.v = *(const f16x8*)(pp + 384);
      float n0 = 0.f, n1 = 0.f, n2 = 0.f, n3 = 0.f;
      #pragma unroll
      for (int d = 0; d < 4; ++d) {
        n0 = __builtin_amdgcn_fdot2(x0.d[d], x0.d[d], n0, false);
        n1 = __builtin_amdgcn_fdot2(x1.d[d], x1.d[d], n1, false);
        n2 = __builtin_amdgcn_fdot2(x2.d[d], x2.d[d], n2, false);
        n3 = __builtin_amdgcn_fdot2(x3.d[d], x3.d[d], n3, false);
      }
      float nsq = (n0 + n1) + (n2 + n3);
      scaleL[tid] = sqrtf(nsq) / (1.f + nsq);
    }
    __syncthreads();
    if (rt < 2) {
      // agreement: thread (w,ii,c); dot(votes,pre) * scale -> logit
      float dot = 0.f;
      #pragma unroll
      for (int q = 0; q < 4; ++q) {
        f16x8u vv, aa;
        vv.v = *(const f16x8*)(smem + aw * 4352 + aii * 544 +
                               (q * 8 + (((ac + q) & 7) ^ aii)) * 16);
        aa.v = *(const f16x8*)(smem + 17408 + aw * 512 + q * 128 + ac * 16);
        #pragma unroll
        for (int d = 0; d < 4; ++d)
          dot = __builtin_amdgcn_fdot2(vv.d[d], aa.d[d], dot, false);
      }
      float ds = dot * scaleL[aw * 8 + ac];
      int idx = (aw * 8 + aii) * 8 + ac;
      if (rt == 0) logitL[idx] = ds;
      else         logitL[idx] += ds;
      __syncthreads();
    } else {
      #pragma unroll
      for (int w = 0; w < 4; ++w)
        out[((size_t)((bb * 32 + h) * 32 + wq * 4 + w)) * 256 + tid] =
            pre[w] * scaleL[w * 8 + c_t];
    }
  }
}

extern "C" void kernel_launch(void* const* d_in, const int* in_sizes, int n_in,
                              void* d_out, int out_size, void* d_ws, size_t ws_size,
                              hipStream_t stream) {
  (void)in_sizes; (void)n_in; (void)ws_size; (void)out_size;
  const float* inp  = (const float*)d_in[0];
  const float* W    = (const float*)d_in[1];
  const float* bv   = (const float*)d_in[2];
  float* out        = (float*)d_out;
  unsigned short* wsh = (unsigned short*)d_ws;   // 204800 B used

  hipLaunchKernelGGL(wprep_kernel, dim3(400), dim3(256), 0, stream, W, wsh);
  hipLaunchKernelGGL(capsconv_mfma_kernel, dim3(4096), dim3(256), 0, stream,
                     inp, wsh, bv, out);
}